// Round 12
// baseline (718.345 us; speedup 1.0000x reference)
//
#include <hip/hip_runtime.h>
#include <stdint.h>

typedef __attribute__((ext_vector_type(8))) short short8;
typedef __attribute__((ext_vector_type(4))) short short4v;
typedef __attribute__((ext_vector_type(4))) float f32x4;

#define DEVINL __device__ __forceinline__

DEVINL unsigned short f2bf(float x) {
  uint32_t b = __float_as_uint(x);
  b += 0x7fffu + ((b >> 16) & 1u);
  return (unsigned short)(b >> 16);
}
DEVINL float bf2f(unsigned short u) {
  return __uint_as_float(((uint32_t)u) << 16);
}

DEVINL void gll16(const void* g, void* l) {
  __builtin_amdgcn_global_load_lds(
      (const __attribute__((address_space(1))) uint32_t*)g,
      (__attribute__((address_space(3))) uint32_t*)l, 16, 0, 0);
}

__global__ void cvt_w_bf16(const float* __restrict__ in,
                           unsigned short* __restrict__ out, int n) {
  int i = blockIdx.x * blockDim.x + threadIdx.x;
  int stride = gridDim.x * blockDim.x;
  for (; i < n; i += stride) out[i] = f2bf(in[i]);
}

// wave-per-row: out_row = bf16(in_row / (||in_row|| + eps))
template <int D>
__global__ __launch_bounds__(256) void norm_rows_f32(
    const float* __restrict__ in, unsigned short* __restrict__ out, int nrows) {
  const int lane = threadIdx.x & 63;
  const int row = blockIdx.x * 4 + (threadIdx.x >> 6);
  if (row >= nrows) return;
  const float* r = in + (size_t)row * D;
  constexpr int NSEG = D / 256;
  f32x4 v[NSEG];
  float ssq = 0.f;
#pragma unroll
  for (int i = 0; i < NSEG; ++i) {
    v[i] = *(const f32x4*)(r + (i * 64 + lane) * 4);
#pragma unroll
    for (int j = 0; j < 4; ++j) ssq += v[i][j] * v[i][j];
  }
#pragma unroll
  for (int m = 32; m >= 1; m >>= 1) ssq += __shfl_xor(ssq, m, 64);
  const float sc = 1.0f / (sqrtf(ssq) + 1e-8f);
  unsigned short* o = out + (size_t)row * D;
#pragma unroll
  for (int i = 0; i < NSEG; ++i) {
    short4v u;
#pragma unroll
    for (int j = 0; j < 4; ++j) u[j] = (short)f2bf(v[i][j] * sc);
    *(short4v*)(o + (i * 64 + lane) * 4) = u;
  }
}

// wave-per-row: scale[row] = 1/(||bf16 row|| + eps)
template <int H>
__global__ __launch_bounds__(256) void rownorm_bf16(
    const unsigned short* __restrict__ in, float* __restrict__ scale, int nrows) {
  const int lane = threadIdx.x & 63;
  const int row = blockIdx.x * 4 + (threadIdx.x >> 6);
  if (row >= nrows) return;
  const unsigned short* r = in + (size_t)row * H;
  constexpr int NSEG = H / 512;
  float ssq = 0.f;
#pragma unroll
  for (int i = 0; i < NSEG; ++i) {
    short8 u = *(const short8*)(r + (i * 64 + lane) * 8);
#pragma unroll
    for (int j = 0; j < 8; ++j) {
      float f = bf2f((unsigned short)u[j]);
      ssq += f * f;
    }
  }
#pragma unroll
  for (int m = 32; m >= 1; m >>= 1) ssq += __shfl_xor(ssq, m, 64);
  if (lane == 0) scale[row] = 1.0f / (sqrtf(ssq) + 1e-8f);
}

// 256x256 3-slot-ring GEMM, BK=32, ONE barrier + ONE counted vmcnt per
// K-tile. 8 waves (2Mx4N), per-wave C = 128x64 (acc 8x4). LDS = 3 slots x
// (A[256][32] | B[256][32]) = 96 KiB. Per K-tile: stage tile t+2 (4x 8KB
// gll16) -> 12 ds_read_b128 -> 32 MFMA (one k-slice, all independent) ->
// vmcnt(4) [outstanding = t+1's 4 (oldest) + t+2's 4 -> drains exactly
// t+1, NEVER 0] -> s_barrier -> rotate slots. No mid-tile publishes:
// everything a tile reads landed at its opening barrier (eliminates the
// r9 consumption-map race class). Jail-region ratio 32 MFMA : 12 reads
// (vs r11's 16:16) lets the compiler's auto counted-lgkmcnt stream MFMAs
// against in-flight ds_reads inside the region.
// Ring reuse: slot(t+2) = slot(t-1); t-1's reads retired before its
// closing barrier (consumed by MFMAs before it), stage(t+2) issued after
// that barrier (r8-validated argument).
// T2 swizzle (BK=32, 64B rows): stored 16B-unit at pos p of row r is
// global unit p^(r&3) (pre-swizzled source, LDS linear for gll16);
// ds_read pos u^(r&3), u=lane>>4, r&3==lane&3. Bank check: addr/4 =
// r*16 + pos*4 + d -> (r&1)*16 + pos*4 + d mod 32; per bank exactly 8
// dwords per wave-b128 = minimum (conflict-free).
template <bool SCALE, bool RELU, bool OUT_BF16>
__global__ __launch_bounds__(512, 1) void gemm_r3(
    const unsigned short* __restrict__ A, const unsigned short* __restrict__ Bw,
    const float* __restrict__ bias, const float* __restrict__ scaleArr,
    void* __restrict__ Cptr, int M, int N, int K) {
  extern __shared__ __align__(16) short lds[];  // 3 x 16384 shorts
  constexpr int SLOT = 16384;
  constexpr int BOFF = 8192;

  const int t = threadIdx.x;
  const int lane = t & 63;
  const int wid = t >> 6;   // 0..7
  const int wr = wid >> 2;  // 0..1  (128-row half)
  const int wc = wid & 3;   // 0..3  (64-col quarter)

  const int nwg = gridDim.x;
  const int bid = blockIdx.x;
  int wg = bid;
  if ((nwg & 7) == 0) wg = (bid & 7) * (nwg >> 3) + (bid >> 3);
  const int numBN = N >> 8;
  const int bm = wg / numBN;
  const int bn = wg % numBN;

  // Staging: thread t covers row (t>>2) (+128 for second load), 16B-unit
  // pos t&3. Pre-swizzled source: global unit = (t&3) ^ (row&3);
  // row&3 == (t>>2)&3 for both loads.
  const int rowS = t >> 2;  // 0..127
  const int usrc = ((t & 3) ^ (rowS & 3)) << 3;
  const unsigned short* sA0 = A + (size_t)(bm * 256 + rowS) * K + usrc;
  const unsigned short* sA1 = A + (size_t)(bm * 256 + 128 + rowS) * K + usrc;
  const unsigned short* sB0 = Bw + (size_t)(bn * 256 + rowS) * K + usrc;
  const unsigned short* sB1 = Bw + (size_t)(bn * 256 + 128 + rowS) * K + usrc;
  const int dA0 = t * 8, dA1 = 4096 + t * 8;
  const int dB0 = BOFF + t * 8, dB1 = BOFF + 4096 + t * 8;

  // ds_read: row r, unit u = lane>>4 -> pos u^(r&3); r&3 == lane&3.
  const int sw = lane & 3;
  const int pA = (wr * 128 + (lane & 15)) * 32;
  const int pB = BOFF + (wc * 64 + (lane & 15)) * 32;
  const int pu = ((lane >> 4) ^ sw) * 8;

  f32x4 acc[8][4] = {};
  const int nt = K >> 5;

  // prologue: stage tile 0 -> slot 0, tile 1 -> slot 1
  gll16(sA0, &lds[dA0]);
  gll16(sA1, &lds[dA1]);
  gll16(sB0, &lds[dB0]);
  gll16(sB1, &lds[dB1]);
  gll16(sA0 + 32, &lds[SLOT + dA0]);
  gll16(sA1 + 32, &lds[SLOT + dA1]);
  gll16(sB0 + 32, &lds[SLOT + dB0]);
  gll16(sB1 + 32, &lds[SLOT + dB1]);
  asm volatile("s_waitcnt vmcnt(4)" ::: "memory");  // tile 0 landed
  asm volatile("s_barrier" ::: "memory");

  int oc = 0, om = SLOT, os = 2 * SLOT;  // slots of tiles t, t+1, t+2
  for (int tt = 0; tt < nt; ++tt) {
    // stage tile tt+2 into slot os (wrap at tail: in-bounds, unused,
    // keeps vmcnt uniform)
    int kf = tt + 2;
    if (kf >= nt) kf -= nt;
    const int kn = kf * 32;
    gll16(sA0 + kn, &lds[os + dA0]);
    gll16(sA1 + kn, &lds[os + dA1]);
    gll16(sB0 + kn, &lds[os + dB0]);
    gll16(sB1 + kn, &lds[os + dB1]);
    // compute tile tt from slot oc; read order: a0 then b's so the first
    // MFMA unlocks after 5 reads, each later a-read unlocks 4 MFMAs
    short8 a0 = *(const short8*)&lds[oc + pA + 0 * 512 + pu];
    short8 b0 = *(const short8*)&lds[oc + pB + 0 * 512 + pu];
    short8 b1 = *(const short8*)&lds[oc + pB + 1 * 512 + pu];
    short8 b2 = *(const short8*)&lds[oc + pB + 2 * 512 + pu];
    short8 b3 = *(const short8*)&lds[oc + pB + 3 * 512 + pu];
    short8 a1 = *(const short8*)&lds[oc + pA + 1 * 512 + pu];
    short8 a2 = *(const short8*)&lds[oc + pA + 2 * 512 + pu];
    short8 a3 = *(const short8*)&lds[oc + pA + 3 * 512 + pu];
    short8 a4 = *(const short8*)&lds[oc + pA + 4 * 512 + pu];
    short8 a5 = *(const short8*)&lds[oc + pA + 5 * 512 + pu];
    short8 a6 = *(const short8*)&lds[oc + pA + 6 * 512 + pu];
    short8 a7 = *(const short8*)&lds[oc + pA + 7 * 512 + pu];
    __builtin_amdgcn_s_setprio(1);
#define MF4(m, av)                                                            \
  acc[m][0] = __builtin_amdgcn_mfma_f32_16x16x32_bf16(av, b0, acc[m][0], 0, 0, 0); \
  acc[m][1] = __builtin_amdgcn_mfma_f32_16x16x32_bf16(av, b1, acc[m][1], 0, 0, 0); \
  acc[m][2] = __builtin_amdgcn_mfma_f32_16x16x32_bf16(av, b2, acc[m][2], 0, 0, 0); \
  acc[m][3] = __builtin_amdgcn_mfma_f32_16x16x32_bf16(av, b3, acc[m][3], 0, 0, 0);
    MF4(0, a0)
    MF4(1, a1)
    MF4(2, a2)
    MF4(3, a3)
    MF4(4, a4)
    MF4(5, a5)
    MF4(6, a6)
    MF4(7, a7)
#undef MF4
    __builtin_amdgcn_s_setprio(0);
    // boundary: drain tile tt+1's 4 loads (oldest), keep tt+2's 4 in flight
    asm volatile("s_waitcnt vmcnt(4)" ::: "memory");
    asm volatile("s_barrier" ::: "memory");
    const int tmp = oc;
    oc = om;
    om = os;
    os = tmp;
  }
  asm volatile("s_waitcnt vmcnt(0)" ::: "memory");  // drain wrap-stages

  // epilogue: frag row=(lane>>4)*4+j, col=lane&15
#pragma unroll
  for (int m = 0; m < 8; ++m) {
#pragma unroll
    for (int j = 0; j < 4; ++j) {
      const int rl = wr * 128 + m * 16 + ((lane >> 4) << 2) + j;
      const size_t row = (size_t)bm * 256 + rl;
      float sc = 1.0f;
      if constexpr (SCALE) sc = scaleArr[row];
#pragma unroll
      for (int n = 0; n < 4; ++n) {
        const int col = bn * 256 + wc * 64 + n * 16 + (lane & 15);
        float x = acc[m][n][j];
        if constexpr (SCALE) x *= sc;
        x += bias[col];
        if constexpr (RELU) x = fmaxf(x, 0.f);
        if constexpr (OUT_BF16)
          ((unsigned short*)Cptr)[row * (size_t)N + col] = f2bf(x);
        else
          ((float*)Cptr)[row * (size_t)N + col] = x;
      }
    }
  }
}

// 2-phase GEMM for G3 (tiny-N, memory-bound)
template <int BM, int BN, int WN, bool SCALE, bool RELU, bool OUT_BF16>
__global__ __launch_bounds__(256) void gemm_ff(
    const unsigned short* __restrict__ A, const unsigned short* __restrict__ Bw,
    const float* __restrict__ bias, const float* __restrict__ scaleArr,
    void* __restrict__ Cptr, int M, int N, int K) {
  constexpr int BK = 32;
  constexpr int PTA = BM / 64;
  constexpr int PTB = BN / 64;
  __shared__ short As[BM * BK];
  __shared__ short Bs[BN * BK];

  const int t = threadIdx.x;
  const int lane = t & 63;
  const int wid = t >> 6;
  const int wr = wid / WN;
  const int wc = wid % WN;
  const int bm = blockIdx.x;
  const int bn = blockIdx.y;

  f32x4 acc[4][4] = {};
  const unsigned short* Abase = A + (size_t)bm * BM * K;
  const unsigned short* Bbase = Bw + (size_t)bn * BN * K;
  const int kIters = K / BK;
  for (int kk = 0; kk < kIters; ++kk) {
    const int k0 = kk * BK;
#pragma unroll
    for (int r = 0; r < PTB; ++r) {
      const int s = r * 256 + t;
      gll16(Bbase + (size_t)(s >> 2) * K + k0 + (s & 3) * 8, &Bs[s * 8]);
    }
#pragma unroll
    for (int r = 0; r < PTA; ++r) {
      const int s = r * 256 + t;
      gll16(Abase + (size_t)(s >> 2) * K + k0 + (s & 3) * 8, &As[s * 8]);
    }
    __syncthreads();
    short8 af[4], bfg[4];
#pragma unroll
    for (int m = 0; m < 4; ++m)
      af[m] = *(const short8*)&As[(wr * 64 + m * 16 + (lane & 15)) * BK + ((lane >> 4) * 8)];
#pragma unroll
    for (int n = 0; n < 4; ++n)
      bfg[n] = *(const short8*)&Bs[(wc * 64 + n * 16 + (lane & 15)) * BK + ((lane >> 4) * 8)];
#pragma unroll
    for (int m = 0; m < 4; ++m)
#pragma unroll
      for (int n = 0; n < 4; ++n)
        acc[m][n] = __builtin_amdgcn_mfma_f32_16x16x32_bf16(af[m], bfg[n], acc[m][n], 0, 0, 0);
    __syncthreads();
  }

#pragma unroll
  for (int m = 0; m < 4; ++m) {
#pragma unroll
    for (int j = 0; j < 4; ++j) {
      const int rl = wr * 64 + m * 16 + ((lane >> 4) << 2) + j;
      const size_t row = (size_t)bm * BM + rl;
      float sc = 1.0f;
      if constexpr (SCALE) sc = scaleArr[row];
#pragma unroll
      for (int n = 0; n < 4; ++n) {
        const int col = bn * BN + wc * 64 + n * 16 + (lane & 15);
        float v = acc[m][n][j];
        if constexpr (SCALE) v *= sc;
        v += bias[col];
        if constexpr (RELU) v = fmaxf(v, 0.f);
        if constexpr (OUT_BF16)
          ((unsigned short*)Cptr)[row * (size_t)N + col] = f2bf(v);
        else
          ((float*)Cptr)[row * (size_t)N + col] = v;
      }
    }
  }
}

extern "C" void kernel_launch(void* const* d_in, const int* in_sizes, int n_in,
                              void* d_out, int out_size, void* d_ws, size_t ws_size,
                              hipStream_t stream) {
  const float* states = (const float*)d_in[0];
  const float* W1 = (const float*)d_in[1];
  const float* b1 = (const float*)d_in[2];
  const float* W2 = (const float*)d_in[3];
  const float* b2 = (const float*)d_in[4];
  const float* Wq = (const float*)d_in[5];
  const float* bq = (const float*)d_in[6];
  float* out = (float*)d_out;

  const int D = 1024, H1 = 2048, H2 = 1024, AO = 64;
  const int B = in_sizes[0] / D;

  unsigned short* W1b = (unsigned short*)d_ws;  // [H1][D]
  unsigned short* W2b = W1b + (size_t)H1 * D;   // [H2][H1]
  unsigned short* Wqb = W2b + (size_t)H2 * H1;  // [AO][H2]
  char* dynbase = (char*)(Wqb + (size_t)AO * H2);

  const size_t wbytes = ((size_t)H1 * D + (size_t)H2 * H1 + (size_t)AO * H2) * 2;
  size_t avail = ws_size > wbytes ? ws_size - wbytes : 0;
  const size_t per_row = 4 + (size_t)(D + H1 + H2) * 2;
  long long bc = (long long)(avail / per_row);
  bc = (bc / 256) * 256;
  if (bc <= 0) bc = 256;
  if (bc > B) bc = B;

  float* scale1 = (float*)dynbase;
  unsigned short* sn = (unsigned short*)(scale1 + bc);
  unsigned short* h1 = sn + (size_t)bc * D;
  unsigned short* h2 = h1 + (size_t)bc * H1;

  // allow 96 KiB dynamic LDS (host-side attribute set; capture-safe)
  (void)hipFuncSetAttribute((const void*)gemm_r3<false, true, true>,
                            hipFuncAttributeMaxDynamicSharedMemorySize, 98304);
  (void)hipFuncSetAttribute((const void*)gemm_r3<true, true, true>,
                            hipFuncAttributeMaxDynamicSharedMemorySize, 98304);

  cvt_w_bf16<<<dim3(1024), dim3(256), 0, stream>>>(W1, W1b, H1 * D);
  cvt_w_bf16<<<dim3(1024), dim3(256), 0, stream>>>(W2, W2b, H2 * H1);
  cvt_w_bf16<<<dim3(64), dim3(256), 0, stream>>>(Wq, Wqb, AO * H2);

  for (int off = 0; off < B; off += (int)bc) {
    const int cur = (B - off) < (int)bc ? (B - off) : (int)bc;
    norm_rows_f32<1024><<<dim3(cur / 4), dim3(256), 0, stream>>>(
        states + (size_t)off * D, sn, cur);
    // G1: h1 = relu(sn·W1^T + b1)
    gemm_r3<false, true, true>
        <<<dim3((cur / 256) * (H1 / 256)), dim3(512), 98304, stream>>>(
            sn, W1b, b1, nullptr, h1, cur, H1, D);
    // scale1[row] = 1/(||h1 row||+eps)
    rownorm_bf16<2048><<<dim3(cur / 4), dim3(256), 0, stream>>>(h1, scale1, cur);
    // G2: h2 = relu(scale1·(h1·W2^T) + b2)
    gemm_r3<true, true, true>
        <<<dim3((cur / 256) * (H2 / 256)), dim3(512), 98304, stream>>>(
            h1, W2b, b2, scale1, h2, cur, H2, H1);
    // G3: q = h2·Wq^T + bq
    gemm_ff<256, 64, 1, false, false, false>
        <<<dim3(cur / 256), dim3(256), 0, stream>>>(
            h2, Wqb, bq, nullptr, out + (size_t)off * AO, cur, AO, H2);
  }
}